// Round 5
// baseline (2545.129 us; speedup 1.0000x reference)
//
#include <hip/hip_runtime.h>

typedef __attribute__((ext_vector_type(8))) short bf16x8;
typedef __attribute__((ext_vector_type(4))) float f32x4;
typedef unsigned long long u64;

__device__ __forceinline__ unsigned short f2bf(float x) {
    union { float f; unsigned u; } c; c.f = x;
    unsigned u = c.u + 0x7fffu + ((c.u >> 16) & 1u);
    return (unsigned short)(u >> 16);
}
__device__ __forceinline__ unsigned pack2(float a, float b) {
    return (unsigned)f2bf(a) | ((unsigned)f2bf(b) << 16);
}
__device__ __forceinline__ float sigm(float x) { return 1.f / (1.f + __expf(-x)); }
__device__ __forceinline__ float tanh_(float x) { return 1.f - 2.f / (__expf(2.f * x) + 1.f); }

#define ALOAD(p)     __hip_atomic_load((p), __ATOMIC_RELAXED, __HIP_MEMORY_SCOPE_AGENT)
#define ASTORE(p, v) __hip_atomic_store((p), (v), __ATOMIC_RELAXED, __HIP_MEMORY_SCOPE_AGENT)

// Atomic RMW executes at the L2 point (atomics never complete in L1); without
// sc1 that point is the issuing XCD's L2. Publisher bump and reader poll meet
// at the same cache -> self-consistent visibility, stale-free by construction.
__device__ __forceinline__ unsigned atomic_poll(unsigned* p) {
    unsigned r;
    asm volatile("global_atomic_add %0, %1, %2, off sc0\n\ts_waitcnt vmcnt(0)"
                 : "=v"(r) : "v"(p), "v"(0u) : "memory");
    return r;
}
__device__ __forceinline__ void atomic_bump(unsigned* p) {
    asm volatile("global_atomic_add %0, %1, off\n\ts_waitcnt vmcnt(0)"
                 :: "v"(p), "v"(1u) : "memory");
}

// ---------------------------------------------------------------------------
// prep: table[v][c] = emb[v] . w_ih[srow(c)] + b_ih + b_hh   (c = permuted col)
//       Wp[c][k] = bf16(w_hh[srow(c)][k]);  w1p = bf16(w1)
//       imgb[b][h] = bf16(img_rep[b] . proc_w[h] + proc_b[h])
// Permutation: c -> tile t=c>>7, c7=c&127:
//   unit U = t*32 + ((c7>>6)&1)*16 + (c7&15), gate g=(c7>>4)&3, srow = g*512+U
// ---------------------------------------------------------------------------
__global__ __launch_bounds__(256) void prep_k(
    const float* __restrict__ emb, const float* __restrict__ w_ih,
    const float* __restrict__ b_ih, const float* __restrict__ b_hh,
    const float* __restrict__ w_hh, const float* __restrict__ w1,
    const float* __restrict__ imgr, const float* __restrict__ procw,
    const float* __restrict__ procb,
    float* __restrict__ table, unsigned short* __restrict__ Wp,
    unsigned short* __restrict__ w1p, unsigned short* __restrict__ imgb)
{
    int wg = blockIdx.x, tid = threadIdx.x;
    if (wg < 256) {
        int id = wg * 256 + tid;              // v*2048 + c
        int v = id >> 11, c = id & 2047;
        int c7 = c & 127, tt = c >> 7;
        int srow = ((c7 >> 4) & 3) * 512 + tt * 32 + ((c7 >> 6) & 1) * 16 + (c7 & 15);
        const float4* e4 = (const float4*)(emb + v * 256);
        const float4* w4 = (const float4*)(w_ih + srow * 256);
        float a = 0.f;
        #pragma unroll 8
        for (int k = 0; k < 64; ++k) {
            float4 x = e4[k], y = w4[k];
            a += x.x * y.x + x.y * y.y + x.z * y.z + x.w * y.w;
        }
        table[id] = a + b_ih[srow] + b_hh[srow];
    } else if (wg < 768) {
        int id = (wg - 256) * 256 + tid;      // c*64 + j  (8 elems each)
        int c = id >> 6, j = id & 63;
        int c7 = c & 127, tt = c >> 7;
        int srow = ((c7 >> 4) & 3) * 512 + tt * 32 + ((c7 >> 6) & 1) * 16 + (c7 & 15);
        const float4* s4 = (const float4*)(w_hh + srow * 512 + j * 8);
        float4 x = s4[0], y = s4[1];
        uint4 r;
        r.x = pack2(x.x, x.y); r.y = pack2(x.z, x.w);
        r.z = pack2(y.x, y.y); r.w = pack2(y.z, y.w);
        *(uint4*)(Wp + c * 512 + j * 8) = r;
    } else if (wg < 1024) {
        int id = (wg - 768) * 256 + tid;      // 8 elems each of w1
        const float4* s4 = (const float4*)(w1 + id * 8);
        float4 x = s4[0], y = s4[1];
        uint4 r;
        r.x = pack2(x.x, x.y); r.y = pack2(x.z, x.w);
        r.z = pack2(y.x, y.y); r.w = pack2(y.z, y.w);
        *(uint4*)(w1p + id * 8) = r;
    } else {
        int id = (wg - 1024) * 256 + tid;     // b*512 + h
        int b = id >> 9, h = id & 511;
        const float* ir = imgr + b * 13;
        const float* pw = procw + h * 13;
        float a = procb[h];
        #pragma unroll
        for (int k = 0; k < 13; ++k) a += ir[k] * pw[k];
        imgb[id] = f2bf(a);
    }
}

// ---------------------------------------------------------------------------
// Step loop, templated on FAST. Identical structure; only memory primitives
// differ. FAST: plain stores/loads (local-L2 via write-through L1; h rotates
// through 16 buffers so L1 can never serve a stale line), atomic bump/poll at
// the local L2 point. SLOW: round-3-proven sc1 (IF) path.
// ---------------------------------------------------------------------------
template<int FAST>
__device__ __forceinline__ void steps_loop(
    const uint4* BshF, const float* Tsh, const unsigned char* Msh,
    unsigned short* Hsh, u64* hb, unsigned* myflag, int g, int t)
{
    const int tid = threadIdx.x;
    const int lane = tid & 63, wid = tid >> 6;
    const int wr = wid >> 1, wc = wid & 1;
    const int l15 = lane & 15, l4 = lane >> 4;
    const int arow = g * 64 + wr * 16 + l15;   // A-fragment global row
    const int bbase = wc * 4096;               // wave's B-fragment base (uint4)
    float creg[4] = {0.f, 0.f, 0.f, 0.f};

    for (int s = 0; s < 64; ++s) {
        f32x4 acc[4] = {};
        if (s > 0) {
            const unsigned tgt = (unsigned)s;
            for (;;) {
                unsigned v = FAST ? atomic_poll(&myflag[l15]) : ALOAD(&myflag[l15]);
                if (__all((int)(v >= tgt))) break;
                __builtin_amdgcn_s_sleep(1);
            }
            const u64* hp = hb + (size_t)((s - 1) & 15) * 131072;
            u64 a0[16], a1[16];
            #pragma unroll
            for (int kg = 0; kg < 16; ++kg) {
                int idx = arow * 128 + kg * 8 + l4 * 2;
                if (FAST) { a0[kg] = hp[idx];         a1[kg] = hp[idx + 1]; }
                else      { a0[kg] = ALOAD(&hp[idx]); a1[kg] = ALOAD(&hp[idx + 1]); }
            }
            #pragma unroll
            for (int kg = 0; kg < 16; ++kg) {
                union { u64 u[2]; bf16x8 v; } A;
                A.u[0] = a0[kg]; A.u[1] = a1[kg];
                #pragma unroll
                for (int cf = 0; cf < 4; ++cf) {
                    bf16x8 bfr = *(const bf16x8*)&BshF[bbase + (kg * 4 + cf) * 64 + lane];
                    acc[cf] = __builtin_amdgcn_mfma_f32_16x16x32_bf16(
                        A.v, bfr, acc[cf], 0, 0, 0);
                }
            }
        }
        // fused cell update -> Hsh (LDS transpose for coalesced global store)
        #pragma unroll
        for (int reg = 0; reg < 4; ++reg) {
            int bl = wr * 16 + l4 * 4 + reg;
            int v = Msh[s * 64 + bl];
            const float* tr = Tsh + v * 128 + wc * 64 + l15;
            float gi = acc[0][reg] + tr[0];
            float gf = acc[1][reg] + tr[16];
            float gg = acc[2][reg] + tr[32];
            float go = acc[3][reg] + tr[48];
            float cn = sigm(gf) * creg[reg] + sigm(gi) * tanh_(gg);
            creg[reg] = cn;
            Hsh[bl * 40 + wc * 16 + l15] = f2bf(sigm(go) * tanh_(cn));
        }
        __syncthreads();   // Hsh complete
        {
            int row = tid >> 3, j = tid & 7;
            u64 val = *(const u64*)&Hsh[row * 40 + j * 4];
            u64* hw = hb + (size_t)(s & 15) * 131072;
            if (FAST) hw[(g * 64 + row) * 128 + t * 8 + j] = val;
            else      ASTORE(&hw[(g * 64 + row) * 128 + t * 8 + j], val);
        }
        __syncthreads();   // vmcnt(0) before s_barrier == agent-release of h
        if (tid == 0) {
            if (FAST) atomic_bump(&myflag[t]);
            else      ASTORE(&myflag[t], (unsigned)(s + 1));
        }
    }
}

// ---------------------------------------------------------------------------
// Persistent LSTM: 256 WGs x 512 thr, 1 WG/CU (LDS 153 KB). WG x: group
// g=(x&7)|(((x>>7)&1)<<3) (rows g*64..+64), tile t=(x>>3)&15 (units t*32..+32).
// B in LDS fragment order. Per-group XCD co-location check decides FAST
// (intra-XCD L2 protocol) vs SLOW (sc1/IF, round-3 proven). Verdict is made
// by the t==0 leader with a BOUNDED spin and always published -> no hang.
// ---------------------------------------------------------------------------
__global__ __launch_bounds__(512, 2) void lstm_k(
    const float* __restrict__ table, const unsigned short* __restrict__ Wp,
    const int* __restrict__ msgs, u64* __restrict__ hb,
    unsigned* __restrict__ flags)
{
    extern __shared__ char smem[];
    uint4* BshF = (uint4*)smem;                                // 128 KB fragment order
    float* Tsh  = (float*)(smem + 131072);                     // 16 KB table tile
    unsigned char* Msh = (unsigned char*)(smem + 147456);      // 4 KB msgs
    unsigned short* Hsh = (unsigned short*)(smem + 151552);    // [64][40] u16 = 5 KB

    const int tid = threadIdx.x;
    const int x = blockIdx.x;
    const int g = (x & 7) | (((x >> 7) & 1) << 3);
    const int t = (x >> 3) & 15;

    // ---- stage B into fragment order
    const uint4* wg4 = (const uint4*)Wp;
    #pragma unroll
    for (int it = 0; it < 16; ++it) {
        int p = it * 512 + tid;
        int col = p >> 6, ks = p & 63;
        uint4 v = wg4[(t * 128 + col) * 64 + ks];
        int dst = (((col >> 6) * 16 + (ks >> 2)) * 4 + ((col >> 4) & 3)) * 64
                  + (ks & 3) * 16 + (col & 15);
        BshF[dst] = v;
    }
    // ---- table tile [32 v][128 c7]
    const uint4* tg = (const uint4*)table;
    uint4* T4 = (uint4*)Tsh;
    #pragma unroll
    for (int it = 0; it < 2; ++it) {
        int p = it * 512 + tid;
        T4[p] = tg[(p >> 5) * 512 + t * 32 + (p & 31)];
    }
    // ---- msgs [s][row]
    #pragma unroll
    for (int it = 0; it < 8; ++it) {
        int p = it * 512 + tid;
        int row = p >> 6, s_ = p & 63;
        Msh[s_ * 64 + row] = (unsigned char)msgs[(g * 64 + row) * 64 + s_];
    }
    __syncthreads();

    // ---- per-group XCD co-location verdict (leader-decided, bounded, no hang)
    unsigned* xslots = flags + 256;   // 256 words
    unsigned* verd   = flags + 512;   // 16 words
    volatile unsigned* bc = (volatile unsigned*)Hsh;
    if (tid == 0) {
        unsigned xcd;
        asm volatile("s_getreg_b32 %0, hwreg(HW_REG_XCC_ID)" : "=s"(xcd));
        ASTORE(&xslots[g * 16 + t], xcd + 1u);
        if (t == 0) {
            unsigned ok = 1, first = 0;
            long spins = 0;
            for (int i = 0; i < 16 && ok; ++i) {
                unsigned v;
                for (;;) {
                    v = ALOAD(&xslots[g * 16 + i]);
                    if (v) break;
                    if (++spins > (1 << 20)) { ok = 0; break; }   // bounded
                    __builtin_amdgcn_s_sleep(2);
                }
                if (!ok) break;
                if (i == 0) first = v;
                else if (v != first) ok = 0;
            }
            ASTORE(&verd[g], ok + 1u);   // always published
        }
        unsigned v;
        do {
            v = ALOAD(&verd[g]);
            if (!v) __builtin_amdgcn_s_sleep(2);
        } while (!v);                    // leader always publishes -> terminates
        bc[0] = v - 1;
    }
    __syncthreads();
    unsigned fastu = bc[0];
    __syncthreads();   // everyone read verdict before Hsh reuse

    unsigned* myflag = flags + g * 16;
    if (fastu) steps_loop<1>(BshF, Tsh, Msh, Hsh, hb, myflag, g, t);
    else       steps_loop<0>(BshF, Tsh, Msh, Hsh, hb, myflag, g, t);
}

// ---------------------------------------------------------------------------
// hidden = relu([h64, img] @ w1^T + b1): M=1024,N=512,K=1024. Grid (16,16),
// tile 64x32, 4 waves split M. Plain loads (dispatch-boundary coherence).
// ---------------------------------------------------------------------------
__global__ __launch_bounds__(256) void mlp2_k(
    const u64* __restrict__ hfin, const unsigned short* __restrict__ imgb,
    const unsigned short* __restrict__ w1p, const float* __restrict__ b1,
    float* __restrict__ hid)
{
    __shared__ uint4 ldsA[512];   // [64 rows][8 slots]
    __shared__ uint4 ldsB[256];   // [32 cols][8 slots]
    const int tid = threadIdx.x;
    const int lane = tid & 63, wid = tid >> 6;
    const int l15 = lane & 15, l4 = lane >> 4;
    const int mbase = blockIdx.y * 64;
    const int t = blockIdx.x;     // [0,16)

    const uint4* h4 = (const uint4*)hfin;  // h row = 64 uint4 (K=512)
    const uint4* ia = (const uint4*)imgb;
    const uint4* wb = (const uint4*)w1p;   // rows of 128 uint4

    f32x4 acc[2] = {};
    uint4 ra[2], rb1;

    #pragma unroll
    for (int j = 0; j < 2; ++j) {
        int p = tid + j * 256, row = p >> 3, ss = (p & 7) ^ (row & 7);
        ra[j] = h4[(mbase + row) * 64 + ss];
    }
    {
        int col = tid >> 3, ss = (tid & 7) ^ (col & 7);
        rb1 = wb[(t * 32 + col) * 128 + ss];
    }
    #pragma unroll
    for (int j = 0; j < 2; ++j) ldsA[tid + j * 256] = ra[j];
    ldsB[tid] = rb1;
    __syncthreads();

    for (int kc = 0; kc < 16; ++kc) {
        if (kc < 15) {
            int kn = kc + 1;
            #pragma unroll
            for (int j = 0; j < 2; ++j) {
                int p = tid + j * 256, row = p >> 3, ss = (p & 7) ^ (row & 7);
                ra[j] = (kn < 8) ? h4[(mbase + row) * 64 + kn * 8 + ss]
                                 : ia[(mbase + row) * 64 + (kn - 8) * 8 + ss];
            }
            int col = tid >> 3, ss = (tid & 7) ^ (col & 7);
            rb1 = wb[(t * 32 + col) * 128 + kn * 8 + ss];
        }
        #pragma unroll
        for (int kg = 0; kg < 2; ++kg) {
            int row = wid * 16 + l15;
            bf16x8 af = *(const bf16x8*)&ldsA[row * 8 + ((kg * 4 + l4) ^ (row & 7))];
            #pragma unroll
            for (int cf = 0; cf < 2; ++cf) {
                int col = cf * 16 + l15;
                bf16x8 bf = *(const bf16x8*)&ldsB[col * 8 + ((kg * 4 + l4) ^ (col & 7))];
                acc[cf] = __builtin_amdgcn_mfma_f32_16x16x32_bf16(af, bf, acc[cf], 0, 0, 0);
            }
        }
        if (kc < 15) {
            __syncthreads();
            #pragma unroll
            for (int j = 0; j < 2; ++j) ldsA[tid + j * 256] = ra[j];
            ldsB[tid] = rb1;
            __syncthreads();
        }
    }

    #pragma unroll
    for (int reg = 0; reg < 4; ++reg) {
        int b = mbase + wid * 16 + l4 * 4 + reg;
        #pragma unroll
        for (int cf = 0; cf < 2; ++cf) {
            int n = t * 32 + cf * 16 + l15;
            hid[b * 512 + n] = fmaxf(acc[cf][reg] + b1[n], 0.f);
        }
    }
}

// prediction: one wave per batch row, shuffle-reduce over 512 f32.
__global__ __launch_bounds__(256) void pred2_k(
    const float* __restrict__ hid, const float* __restrict__ w2,
    const float* __restrict__ b2, float* __restrict__ out)
{
    int wid = threadIdx.x >> 6, lane = threadIdx.x & 63;
    int b = blockIdx.x * 4 + wid;
    const float4* hr = (const float4*)(hid + b * 512);
    const float4* wA = (const float4*)(w2);
    const float4* wB = (const float4*)(w2 + 512);
    float a0 = 0.f, a1 = 0.f;
    #pragma unroll
    for (int j = 0; j < 2; ++j) {
        float4 h4 = hr[lane * 2 + j];
        float4 x0 = wA[lane * 2 + j], x1 = wB[lane * 2 + j];
        a0 += h4.x * x0.x + h4.y * x0.y + h4.z * x0.z + h4.w * x0.w;
        a1 += h4.x * x1.x + h4.y * x1.y + h4.z * x1.z + h4.w * x1.w;
    }
    #pragma unroll
    for (int off = 32; off > 0; off >>= 1) {
        a0 += __shfl_xor(a0, off);
        a1 += __shfl_xor(a1, off);
    }
    if (lane == 0) {
        out[b * 2]     = a0 + b2[0];
        out[b * 2 + 1] = a1 + b2[1];
    }
}

// emb output gather: out[b][s][:] = embedding[msg[b][s]][:]
__global__ __launch_bounds__(256) void gather_k(
    const float* __restrict__ emb, const int* __restrict__ msgs,
    float* __restrict__ out)
{
    const float4* e4 = (const float4*)emb;
    float4* o4 = (float4*)out;
    int id = blockIdx.x * 256 + threadIdx.x;
    #pragma unroll
    for (int it = 0; it < 4; ++it) {
        int p = id + it * 1048576;
        int bs = p >> 6, e = p & 63;
        int v = msgs[bs];
        o4[p] = e4[v * 64 + e];
    }
}

extern "C" void kernel_launch(void* const* d_in, const int* in_sizes, int n_in,
                              void* d_out, int out_size, void* d_ws, size_t ws_size,
                              hipStream_t stream)
{
    const float* imgr  = (const float*)d_in[0];
    const int*   msgs  = (const int*)d_in[1];
    const float* emb   = (const float*)d_in[2];
    const float* w_ih  = (const float*)d_in[3];
    const float* w_hh  = (const float*)d_in[4];
    const float* b_ih  = (const float*)d_in[5];
    const float* b_hh  = (const float*)d_in[6];
    const float* procw = (const float*)d_in[7];
    const float* procb = (const float*)d_in[8];
    const float* w1    = (const float*)d_in[9];
    const float* b1    = (const float*)d_in[10];
    const float* w2    = (const float*)d_in[11];
    const float* b2    = (const float*)d_in[12];
    float* outp = (float*)d_out;

    // Layout: table 256K | Wp 2M | h[16] 16M | imgb 1M | w1p 1M | hid 2M | flags 4K
    const size_t OFF_WP   = 262144;
    const size_t OFF_H    = 2359296;
    const size_t OFF_IMGB = OFF_H + 16777216;        // 19136512
    const size_t OFF_W1P  = OFF_IMGB + 1048576;      // 20185088
    const size_t OFF_HID  = OFF_W1P + 1048576;       // 21233664
    const size_t OFF_FLG  = OFF_HID + 2097152;       // 23330816
    const size_t NEED     = OFF_FLG + 4096;          // ~22.3 MB
    // Fallback scratch: emb output region (67 MB) is written LAST by gather_k.
    char* ws = (ws_size >= NEED) ? (char*)d_ws : (char*)(outp + 2048);

    float*          table = (float*)(ws);
    unsigned short* Wp    = (unsigned short*)(ws + OFF_WP);
    u64*            hb    = (u64*)(ws + OFF_H);      // 16 x 1 MB rotation
    unsigned short* imgb  = (unsigned short*)(ws + OFF_IMGB);
    unsigned short* w1p   = (unsigned short*)(ws + OFF_W1P);
    float*          hid   = (float*)(ws + OFF_HID);
    unsigned*       flags = (unsigned*)(ws + OFF_FLG);

    hipMemsetAsync(flags, 0, 4096, stream);
    hipFuncSetAttribute((const void*)lstm_k,
                        hipFuncAttributeMaxDynamicSharedMemorySize, 156672);

    prep_k<<<3072, 256, 0, stream>>>(emb, w_ih, b_ih, b_hh, w_hh, w1, imgr,
                                     procw, procb, table, Wp, w1p, imgb);
    lstm_k<<<256, 512, 156672, stream>>>(table, Wp, msgs, hb, flags);
    // final h is buffer (63 & 15) = 15
    mlp2_k<<<dim3(16, 16), 256, 0, stream>>>(hb + (size_t)15 * 131072, imgb,
                                             w1p, b1, hid);
    pred2_k<<<256, 256, 0, stream>>>(hid, w2, b2, outp);
    gather_k<<<4096, 256, 0, stream>>>(emb, msgs, outp + 2048);
}

// Round 6
// 459.707 us; speedup vs baseline: 5.5364x; 5.5364x over previous
//
#include <hip/hip_runtime.h>

typedef __attribute__((ext_vector_type(8))) short bf16x8;
typedef __attribute__((ext_vector_type(4))) float f32x4;
typedef unsigned long long u64;

__device__ __forceinline__ unsigned short f2bf(float x) {
    union { float f; unsigned u; } c; c.f = x;
    unsigned u = c.u + 0x7fffu + ((c.u >> 16) & 1u);
    return (unsigned short)(u >> 16);
}
__device__ __forceinline__ unsigned pack2(float a, float b) {
    return (unsigned)f2bf(a) | ((unsigned)f2bf(b) << 16);
}
__device__ __forceinline__ float sigm(float x) { return 1.f / (1.f + __expf(-x)); }
__device__ __forceinline__ float tanh_(float x) { return 1.f - 2.f / (__expf(2.f * x) + 1.f); }

#define ALOAD(p)     __hip_atomic_load((p), __ATOMIC_RELAXED, __HIP_MEMORY_SCOPE_AGENT)
#define ASTORE(p, v) __hip_atomic_store((p), (v), __ATOMIC_RELAXED, __HIP_MEMORY_SCOPE_AGENT)

// ---------------------------------------------------------------------------
// prep: table[v][c] = emb[v] . w_ih[srow(c)] + b_ih + b_hh   (c = permuted col)
//       Wp[c][k] = bf16(w_hh[srow(c)][k]);  w1p = bf16(w1)
//       imgb[b][h] = bf16(img_rep[b] . proc_w[h] + proc_b[h])
// Permutation: c -> tile t=c>>7, c7=c&127:
//   unit U = t*32 + ((c7>>6)&1)*16 + (c7&15), gate g=(c7>>4)&3, srow = g*512+U
// ---------------------------------------------------------------------------
__global__ __launch_bounds__(256) void prep_k(
    const float* __restrict__ emb, const float* __restrict__ w_ih,
    const float* __restrict__ b_ih, const float* __restrict__ b_hh,
    const float* __restrict__ w_hh, const float* __restrict__ w1,
    const float* __restrict__ imgr, const float* __restrict__ procw,
    const float* __restrict__ procb,
    float* __restrict__ table, unsigned short* __restrict__ Wp,
    unsigned short* __restrict__ w1p, unsigned short* __restrict__ imgb)
{
    int wg = blockIdx.x, tid = threadIdx.x;
    if (wg < 256) {
        int id = wg * 256 + tid;              // v*2048 + c
        int v = id >> 11, c = id & 2047;
        int c7 = c & 127, tt = c >> 7;
        int srow = ((c7 >> 4) & 3) * 512 + tt * 32 + ((c7 >> 6) & 1) * 16 + (c7 & 15);
        const float4* e4 = (const float4*)(emb + v * 256);
        const float4* w4 = (const float4*)(w_ih + srow * 256);
        float a = 0.f;
        #pragma unroll 8
        for (int k = 0; k < 64; ++k) {
            float4 x = e4[k], y = w4[k];
            a += x.x * y.x + x.y * y.y + x.z * y.z + x.w * y.w;
        }
        table[id] = a + b_ih[srow] + b_hh[srow];
    } else if (wg < 768) {
        int id = (wg - 256) * 256 + tid;      // c*64 + j  (8 elems each)
        int c = id >> 6, j = id & 63;
        int c7 = c & 127, tt = c >> 7;
        int srow = ((c7 >> 4) & 3) * 512 + tt * 32 + ((c7 >> 6) & 1) * 16 + (c7 & 15);
        const float4* s4 = (const float4*)(w_hh + srow * 512 + j * 8);
        float4 x = s4[0], y = s4[1];
        uint4 r;
        r.x = pack2(x.x, x.y); r.y = pack2(x.z, x.w);
        r.z = pack2(y.x, y.y); r.w = pack2(y.z, y.w);
        *(uint4*)(Wp + c * 512 + j * 8) = r;
    } else if (wg < 1024) {
        int id = (wg - 768) * 256 + tid;      // 8 elems each of w1
        const float4* s4 = (const float4*)(w1 + id * 8);
        float4 x = s4[0], y = s4[1];
        uint4 r;
        r.x = pack2(x.x, x.y); r.y = pack2(x.z, x.w);
        r.z = pack2(y.x, y.y); r.w = pack2(y.z, y.w);
        *(uint4*)(w1p + id * 8) = r;
    } else {
        int id = (wg - 1024) * 256 + tid;     // b*512 + h
        int b = id >> 9, h = id & 511;
        const float* ir = imgr + b * 13;
        const float* pw = procw + h * 13;
        float a = procb[h];
        #pragma unroll
        for (int k = 0; k < 13; ++k) a += ir[k] * pw[k];
        imgb[id] = f2bf(a);
    }
}

// ---------------------------------------------------------------------------
// Step loop, templated on FAST. Sync is IDENTICAL in both paths (round-3
// proven: sc1 load poll + sc1 flag store, pure loads -> no RMW contention).
// Only the h DATA path differs. FAST (group verified on one XCD): plain
// stores (write-through L1 -> local L2) + plain cacheable loads (local L2/L1);
// stale-L1 defeated by rotating h through 8 buffers (reuse distance 8 steps
// ~1 MB streamed through 32 KB L1). SLOW: sc1 loads/stores at IF (round 3).
// ---------------------------------------------------------------------------
template<int FAST>
__device__ __forceinline__ void steps_loop(
    const uint4* BshF, const float* Tsh, const unsigned char* Msh,
    unsigned short* Hsh, u64* hb, unsigned* myflag, int g, int t)
{
    const int tid = threadIdx.x;
    const int lane = tid & 63, wid = tid >> 6;
    const int wr = wid >> 1, wc = wid & 1;
    const int l15 = lane & 15, l4 = lane >> 4;
    const int arow = g * 64 + wr * 16 + l15;   // A-fragment global row
    const int bbase = wc * 4096;               // wave's B-fragment base (uint4)
    float creg[4] = {0.f, 0.f, 0.f, 0.f};

    for (int s = 0; s < 64; ++s) {
        f32x4 acc[4] = {};
        if (s > 0) {
            // poll: 16 lanes cover the group's flag line; pure sc1 loads
            const unsigned tgt = (unsigned)s;
            for (;;) {
                unsigned v = ALOAD(&myflag[l15]);
                if (__all((int)(v >= tgt))) break;
                __builtin_amdgcn_s_sleep(1);
            }
            asm volatile("" ::: "memory");   // pin h loads behind the poll
            const u64* hp = hb + (size_t)((s - 1) & 7) * 131072;
            u64 a0[16], a1[16];
            #pragma unroll
            for (int kg = 0; kg < 16; ++kg) {
                int idx = arow * 128 + kg * 8 + l4 * 2;
                if (FAST) { a0[kg] = hp[idx];         a1[kg] = hp[idx + 1]; }
                else      { a0[kg] = ALOAD(&hp[idx]); a1[kg] = ALOAD(&hp[idx + 1]); }
            }
            #pragma unroll
            for (int kg = 0; kg < 16; ++kg) {
                union { u64 u[2]; bf16x8 v; } A;
                A.u[0] = a0[kg]; A.u[1] = a1[kg];
                #pragma unroll
                for (int cf = 0; cf < 4; ++cf) {
                    bf16x8 bfr = *(const bf16x8*)&BshF[bbase + (kg * 4 + cf) * 64 + lane];
                    acc[cf] = __builtin_amdgcn_mfma_f32_16x16x32_bf16(
                        A.v, bfr, acc[cf], 0, 0, 0);
                }
            }
        }
        // fused cell update -> Hsh (LDS transpose for coalesced global store)
        #pragma unroll
        for (int reg = 0; reg < 4; ++reg) {
            int bl = wr * 16 + l4 * 4 + reg;
            int v = Msh[s * 64 + bl];
            const float* tr = Tsh + v * 128 + wc * 64 + l15;
            float gi = acc[0][reg] + tr[0];
            float gf = acc[1][reg] + tr[16];
            float gg = acc[2][reg] + tr[32];
            float go = acc[3][reg] + tr[48];
            float cn = sigm(gf) * creg[reg] + sigm(gi) * tanh_(gg);
            creg[reg] = cn;
            Hsh[bl * 40 + wc * 16 + l15] = f2bf(sigm(go) * tanh_(cn));
        }
        __syncthreads();   // Hsh complete
        {
            int row = tid >> 3, j = tid & 7;
            u64 val = *(const u64*)&Hsh[row * 40 + j * 4];
            u64* hw = hb + (size_t)(s & 7) * 131072;
            if (FAST) hw[(g * 64 + row) * 128 + t * 8 + j] = val;
            else      ASTORE(&hw[(g * 64 + row) * 128 + t * 8 + j], val);
        }
        __syncthreads();   // vmcnt(0) before s_barrier: stores acked (L2/IF)
        if (tid == 0) ASTORE(&myflag[t], (unsigned)(s + 1));
    }
}

// ---------------------------------------------------------------------------
// Persistent LSTM: 256 WGs x 512 thr, 1 WG/CU (LDS 153 KB). WG x: group
// g=(x&7)|(((x>>7)&1)<<3) (rows g*64..+64), tile t=(x>>3)&15 (units t*32..+32).
// B in LDS fragment order. Per-group XCD co-location verdict (leader-decided,
// bounded spin, always published -> hang-free) selects FAST local-L2 data
// path vs SLOW sc1/IF path (round-3 proven).
// ---------------------------------------------------------------------------
__global__ __launch_bounds__(512, 2) void lstm_k(
    const float* __restrict__ table, const unsigned short* __restrict__ Wp,
    const int* __restrict__ msgs, u64* __restrict__ hb,
    unsigned* __restrict__ flags)
{
    extern __shared__ char smem[];
    uint4* BshF = (uint4*)smem;                                // 128 KB fragment order
    float* Tsh  = (float*)(smem + 131072);                     // 16 KB table tile
    unsigned char* Msh = (unsigned char*)(smem + 147456);      // 4 KB msgs
    unsigned short* Hsh = (unsigned short*)(smem + 151552);    // [64][40] u16 = 5 KB

    const int tid = threadIdx.x;
    const int x = blockIdx.x;
    const int g = (x & 7) | (((x >> 7) & 1) << 3);
    const int t = (x >> 3) & 15;

    // ---- stage B into fragment order
    const uint4* wg4 = (const uint4*)Wp;
    #pragma unroll
    for (int it = 0; it < 16; ++it) {
        int p = it * 512 + tid;
        int col = p >> 6, ks = p & 63;
        uint4 v = wg4[(t * 128 + col) * 64 + ks];
        int dst = (((col >> 6) * 16 + (ks >> 2)) * 4 + ((col >> 4) & 3)) * 64
                  + (ks & 3) * 16 + (col & 15);
        BshF[dst] = v;
    }
    // ---- table tile [32 v][128 c7]
    const uint4* tg = (const uint4*)table;
    uint4* T4 = (uint4*)Tsh;
    #pragma unroll
    for (int it = 0; it < 2; ++it) {
        int p = it * 512 + tid;
        T4[p] = tg[(p >> 5) * 512 + t * 32 + (p & 31)];
    }
    // ---- msgs [s][row]
    #pragma unroll
    for (int it = 0; it < 8; ++it) {
        int p = it * 512 + tid;
        int row = p >> 6, s_ = p & 63;
        Msh[s_ * 64 + row] = (unsigned char)msgs[(g * 64 + row) * 64 + s_];
    }
    __syncthreads();

    // ---- per-group XCD co-location verdict (leader-decided, bounded, no hang)
    unsigned* xslots = flags + 256;   // 256 words
    unsigned* verd   = flags + 512;   // 16 words
    volatile unsigned* bc = (volatile unsigned*)Hsh;
    if (tid == 0) {
        unsigned xcd;
        asm volatile("s_getreg_b32 %0, hwreg(HW_REG_XCC_ID)" : "=s"(xcd));
        ASTORE(&xslots[g * 16 + t], xcd + 1u);
        if (t == 0) {
            unsigned ok = 1, first = 0;
            long spins = 0;
            for (int i = 0; i < 16 && ok; ++i) {
                unsigned v;
                for (;;) {
                    v = ALOAD(&xslots[g * 16 + i]);
                    if (v) break;
                    if (++spins > (1 << 20)) { ok = 0; break; }   // bounded
                    __builtin_amdgcn_s_sleep(2);
                }
                if (!ok) break;
                if (i == 0) first = v;
                else if (v != first) ok = 0;
            }
            ASTORE(&verd[g], ok + 1u);   // always published
        }
        unsigned v;
        do {
            v = ALOAD(&verd[g]);
            if (!v) __builtin_amdgcn_s_sleep(2);
        } while (!v);                    // leader always publishes -> terminates
        bc[0] = v - 1;
    }
    __syncthreads();
    unsigned fastu = bc[0];
    __syncthreads();   // everyone read verdict before Hsh reuse

    unsigned* myflag = flags + g * 16;
    if (fastu) steps_loop<1>(BshF, Tsh, Msh, Hsh, hb, myflag, g, t);
    else       steps_loop<0>(BshF, Tsh, Msh, Hsh, hb, myflag, g, t);
}

// ---------------------------------------------------------------------------
// hidden = relu([h64, img] @ w1^T + b1): M=1024,N=512,K=1024. Grid (16,16),
// tile 64x32, 4 waves split M. Plain loads (dispatch-boundary coherence).
// ---------------------------------------------------------------------------
__global__ __launch_bounds__(256) void mlp2_k(
    const u64* __restrict__ hfin, const unsigned short* __restrict__ imgb,
    const unsigned short* __restrict__ w1p, const float* __restrict__ b1,
    float* __restrict__ hid)
{
    __shared__ uint4 ldsA[512];   // [64 rows][8 slots]
    __shared__ uint4 ldsB[256];   // [32 cols][8 slots]
    const int tid = threadIdx.x;
    const int lane = tid & 63, wid = tid >> 6;
    const int l15 = lane & 15, l4 = lane >> 4;
    const int mbase = blockIdx.y * 64;
    const int t = blockIdx.x;     // [0,16)

    const uint4* h4 = (const uint4*)hfin;  // h row = 64 uint4 (K=512)
    const uint4* ia = (const uint4*)imgb;
    const uint4* wb = (const uint4*)w1p;   // rows of 128 uint4

    f32x4 acc[2] = {};
    uint4 ra[2], rb1;

    #pragma unroll
    for (int j = 0; j < 2; ++j) {
        int p = tid + j * 256, row = p >> 3, ss = (p & 7) ^ (row & 7);
        ra[j] = h4[(mbase + row) * 64 + ss];
    }
    {
        int col = tid >> 3, ss = (tid & 7) ^ (col & 7);
        rb1 = wb[(t * 32 + col) * 128 + ss];
    }
    #pragma unroll
    for (int j = 0; j < 2; ++j) ldsA[tid + j * 256] = ra[j];
    ldsB[tid] = rb1;
    __syncthreads();

    for (int kc = 0; kc < 16; ++kc) {
        if (kc < 15) {
            int kn = kc + 1;
            #pragma unroll
            for (int j = 0; j < 2; ++j) {
                int p = tid + j * 256, row = p >> 3, ss = (p & 7) ^ (row & 7);
                ra[j] = (kn < 8) ? h4[(mbase + row) * 64 + kn * 8 + ss]
                                 : ia[(mbase + row) * 64 + (kn - 8) * 8 + ss];
            }
            int col = tid >> 3, ss = (tid & 7) ^ (col & 7);
            rb1 = wb[(t * 32 + col) * 128 + kn * 8 + ss];
        }
        #pragma unroll
        for (int kg = 0; kg < 2; ++kg) {
            int row = wid * 16 + l15;
            bf16x8 af = *(const bf16x8*)&ldsA[row * 8 + ((kg * 4 + l4) ^ (row & 7))];
            #pragma unroll
            for (int cf = 0; cf < 2; ++cf) {
                int col = cf * 16 + l15;
                bf16x8 bf = *(const bf16x8*)&ldsB[col * 8 + ((kg * 4 + l4) ^ (col & 7))];
                acc[cf] = __builtin_amdgcn_mfma_f32_16x16x32_bf16(af, bf, acc[cf], 0, 0, 0);
            }
        }
        if (kc < 15) {
            __syncthreads();
            #pragma unroll
            for (int j = 0; j < 2; ++j) ldsA[tid + j * 256] = ra[j];
            ldsB[tid] = rb1;
            __syncthreads();
        }
    }

    #pragma unroll
    for (int reg = 0; reg < 4; ++reg) {
        int b = mbase + wid * 16 + l4 * 4 + reg;
        #pragma unroll
        for (int cf = 0; cf < 2; ++cf) {
            int n = t * 32 + cf * 16 + l15;
            hid[b * 512 + n] = fmaxf(acc[cf][reg] + b1[n], 0.f);
        }
    }
}

// prediction: one wave per batch row, shuffle-reduce over 512 f32.
__global__ __launch_bounds__(256) void pred2_k(
    const float* __restrict__ hid, const float* __restrict__ w2,
    const float* __restrict__ b2, float* __restrict__ out)
{
    int wid = threadIdx.x >> 6, lane = threadIdx.x & 63;
    int b = blockIdx.x * 4 + wid;
    const float4* hr = (const float4*)(hid + b * 512);
    const float4* wA = (const float4*)(w2);
    const float4* wB = (const float4*)(w2 + 512);
    float a0 = 0.f, a1 = 0.f;
    #pragma unroll
    for (int j = 0; j < 2; ++j) {
        float4 h4 = hr[lane * 2 + j];
        float4 x0 = wA[lane * 2 + j], x1 = wB[lane * 2 + j];
        a0 += h4.x * x0.x + h4.y * x0.y + h4.z * x0.z + h4.w * x0.w;
        a1 += h4.x * x1.x + h4.y * x1.y + h4.z * x1.z + h4.w * x1.w;
    }
    #pragma unroll
    for (int off = 32; off > 0; off >>= 1) {
        a0 += __shfl_xor(a0, off);
        a1 += __shfl_xor(a1, off);
    }
    if (lane == 0) {
        out[b * 2]     = a0 + b2[0];
        out[b * 2 + 1] = a1 + b2[1];
    }
}

// emb output gather: out[b][s][:] = embedding[msg[b][s]][:]
__global__ __launch_bounds__(256) void gather_k(
    const float* __restrict__ emb, const int* __restrict__ msgs,
    float* __restrict__ out)
{
    const float4* e4 = (const float4*)emb;
    float4* o4 = (float4*)out;
    int id = blockIdx.x * 256 + threadIdx.x;
    #pragma unroll
    for (int it = 0; it < 4; ++it) {
        int p = id + it * 1048576;
        int bs = p >> 6, e = p & 63;
        int v = msgs[bs];
        o4[p] = e4[v * 64 + e];
    }
}

extern "C" void kernel_launch(void* const* d_in, const int* in_sizes, int n_in,
                              void* d_out, int out_size, void* d_ws, size_t ws_size,
                              hipStream_t stream)
{
    const float* imgr  = (const float*)d_in[0];
    const int*   msgs  = (const int*)d_in[1];
    const float* emb   = (const float*)d_in[2];
    const float* w_ih  = (const float*)d_in[3];
    const float* w_hh  = (const float*)d_in[4];
    const float* b_ih  = (const float*)d_in[5];
    const float* b_hh  = (const float*)d_in[6];
    const float* procw = (const float*)d_in[7];
    const float* procb = (const float*)d_in[8];
    const float* w1    = (const float*)d_in[9];
    const float* b1    = (const float*)d_in[10];
    const float* w2    = (const float*)d_in[11];
    const float* b2    = (const float*)d_in[12];
    float* outp = (float*)d_out;

    // Layout: table 256K | Wp 2M | h[8] 8M | imgb 1M | w1p 1M | hid 2M | flags 4K
    const size_t OFF_WP   = 262144;
    const size_t OFF_H    = 2359296;
    const size_t OFF_IMGB = OFF_H + 8388608;         // 10747904
    const size_t OFF_W1P  = OFF_IMGB + 1048576;      // 11796480
    const size_t OFF_HID  = OFF_W1P + 1048576;       // 12845056
    const size_t OFF_FLG  = OFF_HID + 2097152;       // 14942208
    const size_t NEED     = OFF_FLG + 4096;          // ~14.3 MB
    // Fallback scratch: emb output region (67 MB) is written LAST by gather_k.
    char* ws = (ws_size >= NEED) ? (char*)d_ws : (char*)(outp + 2048);

    float*          table = (float*)(ws);
    unsigned short* Wp    = (unsigned short*)(ws + OFF_WP);
    u64*            hb    = (u64*)(ws + OFF_H);      // 8 x 1 MB rotation
    unsigned short* imgb  = (unsigned short*)(ws + OFF_IMGB);
    unsigned short* w1p   = (unsigned short*)(ws + OFF_W1P);
    float*          hid   = (float*)(ws + OFF_HID);
    unsigned*       flags = (unsigned*)(ws + OFF_FLG);

    hipMemsetAsync(flags, 0, 4096, stream);
    hipFuncSetAttribute((const void*)lstm_k,
                        hipFuncAttributeMaxDynamicSharedMemorySize, 156672);

    prep_k<<<3072, 256, 0, stream>>>(emb, w_ih, b_ih, b_hh, w_hh, w1, imgr,
                                     procw, procb, table, Wp, w1p, imgb);
    lstm_k<<<256, 512, 156672, stream>>>(table, Wp, msgs, hb, flags);
    // final h is buffer (63 & 7) = 7
    mlp2_k<<<dim3(16, 16), 256, 0, stream>>>(hb + (size_t)7 * 131072, imgb,
                                             w1p, b1, hid);
    pred2_k<<<256, 256, 0, stream>>>(hid, w2, b2, outp);
    gather_k<<<4096, 256, 0, stream>>>(emb, msgs, outp + 2048);
}

// Round 7
// 454.880 us; speedup vs baseline: 5.5952x; 1.0106x over previous
//
#include <hip/hip_runtime.h>

typedef __attribute__((ext_vector_type(8))) short bf16x8;
typedef __attribute__((ext_vector_type(4))) float f32x4;
typedef unsigned long long u64;

__device__ __forceinline__ unsigned short f2bf(float x) {
    union { float f; unsigned u; } c; c.f = x;
    unsigned u = c.u + 0x7fffu + ((c.u >> 16) & 1u);
    return (unsigned short)(u >> 16);
}
__device__ __forceinline__ unsigned pack2(float a, float b) {
    return (unsigned)f2bf(a) | ((unsigned)f2bf(b) << 16);
}
__device__ __forceinline__ float sigm(float x) { return 1.f / (1.f + __expf(-x)); }
__device__ __forceinline__ float tanh_(float x) { return 1.f - 2.f / (__expf(2.f * x) + 1.f); }

#define ALOAD(p)     __hip_atomic_load((p), __ATOMIC_RELAXED, __HIP_MEMORY_SCOPE_AGENT)
#define ASTORE(p, v) __hip_atomic_store((p), (v), __ATOMIC_RELAXED, __HIP_MEMORY_SCOPE_AGENT)

// ---------------------------------------------------------------------------
// prep: table[v][c] = emb[v] . w_ih[srow(c)] + b_ih + b_hh   (c = permuted col)
//       Wp[c][k] = bf16(w_hh[srow(c)][k]);  w1p = bf16(w1)
//       imgb[b][h] = bf16(img_rep[b] . proc_w[h] + proc_b[h])
// Permutation: c -> tile t=c>>7, c7=c&127:
//   unit U = t*32 + ((c7>>6)&1)*16 + (c7&15), gate g=(c7>>4)&3, srow = g*512+U
// ---------------------------------------------------------------------------
__global__ __launch_bounds__(256) void prep_k(
    const float* __restrict__ emb, const float* __restrict__ w_ih,
    const float* __restrict__ b_ih, const float* __restrict__ b_hh,
    const float* __restrict__ w_hh, const float* __restrict__ w1,
    const float* __restrict__ imgr, const float* __restrict__ procw,
    const float* __restrict__ procb,
    float* __restrict__ table, unsigned short* __restrict__ Wp,
    unsigned short* __restrict__ w1p, unsigned short* __restrict__ imgb)
{
    int wg = blockIdx.x, tid = threadIdx.x;
    if (wg < 256) {
        int id = wg * 256 + tid;              // v*2048 + c
        int v = id >> 11, c = id & 2047;
        int c7 = c & 127, tt = c >> 7;
        int srow = ((c7 >> 4) & 3) * 512 + tt * 32 + ((c7 >> 6) & 1) * 16 + (c7 & 15);
        const float4* e4 = (const float4*)(emb + v * 256);
        const float4* w4 = (const float4*)(w_ih + srow * 256);
        float a = 0.f;
        #pragma unroll 8
        for (int k = 0; k < 64; ++k) {
            float4 x = e4[k], y = w4[k];
            a += x.x * y.x + x.y * y.y + x.z * y.z + x.w * y.w;
        }
        table[id] = a + b_ih[srow] + b_hh[srow];
    } else if (wg < 768) {
        int id = (wg - 256) * 256 + tid;      // c*64 + j  (8 elems each)
        int c = id >> 6, j = id & 63;
        int c7 = c & 127, tt = c >> 7;
        int srow = ((c7 >> 4) & 3) * 512 + tt * 32 + ((c7 >> 6) & 1) * 16 + (c7 & 15);
        const float4* s4 = (const float4*)(w_hh + srow * 512 + j * 8);
        float4 x = s4[0], y = s4[1];
        uint4 r;
        r.x = pack2(x.x, x.y); r.y = pack2(x.z, x.w);
        r.z = pack2(y.x, y.y); r.w = pack2(y.z, y.w);
        *(uint4*)(Wp + c * 512 + j * 8) = r;
    } else if (wg < 1024) {
        int id = (wg - 768) * 256 + tid;      // 8 elems each of w1
        const float4* s4 = (const float4*)(w1 + id * 8);
        float4 x = s4[0], y = s4[1];
        uint4 r;
        r.x = pack2(x.x, x.y); r.y = pack2(x.z, x.w);
        r.z = pack2(y.x, y.y); r.w = pack2(y.z, y.w);
        *(uint4*)(w1p + id * 8) = r;
    } else {
        int id = (wg - 1024) * 256 + tid;     // b*512 + h
        int b = id >> 9, h = id & 511;
        const float* ir = imgr + b * 13;
        const float* pw = procw + h * 13;
        float a = procb[h];
        #pragma unroll
        for (int k = 0; k < 13; ++k) a += ir[k] * pw[k];
        imgb[id] = f2bf(a);
    }
}

// ---------------------------------------------------------------------------
// Step loop, templated on FAST. Sync point semantics unchanged from the
// proven design (sc1 flag store at IF; sc1 load polling). FAST change this
// round: ONLY WAVE 0 POLLS (tight loop, no sleep) then releases the WG via
// __syncthreads -> 8x fewer IF polling agents (contention hypothesis A/B).
// h data: FAST = plain stores/loads via local XCD L2 (L1 staleness defeated
// by 8-buffer rotation); SLOW = sc1 at IF (round-3 proven, byte-identical).
// ---------------------------------------------------------------------------
template<int FAST>
__device__ __forceinline__ void steps_loop(
    const uint4* BshF, const float* Tsh, const unsigned char* Msh,
    unsigned short* Hsh, u64* hb, unsigned* myflag, int g, int t)
{
    const int tid = threadIdx.x;
    const int lane = tid & 63, wid = tid >> 6;
    const int wr = wid >> 1, wc = wid & 1;
    const int l15 = lane & 15, l4 = lane >> 4;
    const int arow = g * 64 + wr * 16 + l15;   // A-fragment global row
    const int bbase = wc * 4096;               // wave's B-fragment base (uint4)
    float creg[4] = {0.f, 0.f, 0.f, 0.f};

    for (int s = 0; s < 64; ++s) {
        f32x4 acc[4] = {};
        if (s > 0) {
            const unsigned tgt = (unsigned)s;
            if (FAST) {
                // single polling wave, tight loop; others park at the barrier
                if (wid == 0) {
                    for (;;) {
                        unsigned v = ALOAD(&myflag[l15]);
                        if (__all((int)(v >= tgt))) break;
                    }
                }
                __syncthreads();
            } else {
                for (;;) {
                    unsigned v = ALOAD(&myflag[l15]);
                    if (__all((int)(v >= tgt))) break;
                    __builtin_amdgcn_s_sleep(1);
                }
                asm volatile("" ::: "memory");   // pin h loads behind the poll
            }
            if (FAST) {
                const uint4* hp4 = (const uint4*)(hb + (size_t)((s - 1) & 7) * 131072);
                uint4 A[16];
                #pragma unroll
                for (int kg = 0; kg < 16; ++kg)
                    A[kg] = hp4[arow * 64 + kg * 4 + l4];
                #pragma unroll
                for (int kg = 0; kg < 16; ++kg) {
                    #pragma unroll
                    for (int cf = 0; cf < 4; ++cf) {
                        bf16x8 bfr = *(const bf16x8*)&BshF[bbase + (kg * 4 + cf) * 64 + lane];
                        acc[cf] = __builtin_amdgcn_mfma_f32_16x16x32_bf16(
                            *(const bf16x8*)&A[kg], bfr, acc[cf], 0, 0, 0);
                    }
                }
            } else {
                const u64* hp = hb + (size_t)((s - 1) & 7) * 131072;
                u64 a0[16], a1[16];
                #pragma unroll
                for (int kg = 0; kg < 16; ++kg) {
                    int idx = arow * 128 + kg * 8 + l4 * 2;
                    a0[kg] = ALOAD(&hp[idx]); a1[kg] = ALOAD(&hp[idx + 1]);
                }
                #pragma unroll
                for (int kg = 0; kg < 16; ++kg) {
                    union { u64 u[2]; bf16x8 v; } A;
                    A.u[0] = a0[kg]; A.u[1] = a1[kg];
                    #pragma unroll
                    for (int cf = 0; cf < 4; ++cf) {
                        bf16x8 bfr = *(const bf16x8*)&BshF[bbase + (kg * 4 + cf) * 64 + lane];
                        acc[cf] = __builtin_amdgcn_mfma_f32_16x16x32_bf16(
                            A.v, bfr, acc[cf], 0, 0, 0);
                    }
                }
            }
        }
        // fused cell update -> Hsh (LDS transpose for coalesced global store)
        #pragma unroll
        for (int reg = 0; reg < 4; ++reg) {
            int bl = wr * 16 + l4 * 4 + reg;
            int v = Msh[s * 64 + bl];
            const float* tr = Tsh + v * 128 + wc * 64 + l15;
            float gi = acc[0][reg] + tr[0];
            float gf = acc[1][reg] + tr[16];
            float gg = acc[2][reg] + tr[32];
            float go = acc[3][reg] + tr[48];
            float cn = sigm(gf) * creg[reg] + sigm(gi) * tanh_(gg);
            creg[reg] = cn;
            Hsh[bl * 40 + wc * 16 + l15] = f2bf(sigm(go) * tanh_(cn));
        }
        __syncthreads();   // Hsh complete
        {
            int row = tid >> 3, j = tid & 7;
            u64 val = *(const u64*)&Hsh[row * 40 + j * 4];
            u64* hw = hb + (size_t)(s & 7) * 131072;
            if (FAST) hw[(g * 64 + row) * 128 + t * 8 + j] = val;
            else      ASTORE(&hw[(g * 64 + row) * 128 + t * 8 + j], val);
        }
        __syncthreads();   // vmcnt(0) before s_barrier: stores acked (L2/IF)
        if (tid == 0) ASTORE(&myflag[t], (unsigned)(s + 1));
    }
}

// ---------------------------------------------------------------------------
// Persistent LSTM: 256 WGs x 512 thr, 1 WG/CU (LDS 153 KB). WG x: group
// g=(x&7)|(((x>>7)&1)<<3) (rows g*64..+64), tile t=(x>>3)&15 (units t*32..+32).
// B in LDS fragment order. Per-group XCD co-location verdict (leader-decided,
// bounded spin, always published -> hang-free) selects FAST local-L2 data
// path vs SLOW sc1/IF path.
// ---------------------------------------------------------------------------
__global__ __launch_bounds__(512, 2) void lstm_k(
    const float* __restrict__ table, const unsigned short* __restrict__ Wp,
    const int* __restrict__ msgs, u64* __restrict__ hb,
    unsigned* __restrict__ flags)
{
    extern __shared__ char smem[];
    uint4* BshF = (uint4*)smem;                                // 128 KB fragment order
    float* Tsh  = (float*)(smem + 131072);                     // 16 KB table tile
    unsigned char* Msh = (unsigned char*)(smem + 147456);      // 4 KB msgs
    unsigned short* Hsh = (unsigned short*)(smem + 151552);    // [64][40] u16 = 5 KB

    const int tid = threadIdx.x;
    const int x = blockIdx.x;
    const int g = (x & 7) | (((x >> 7) & 1) << 3);
    const int t = (x >> 3) & 15;

    // ---- stage B into fragment order
    const uint4* wg4 = (const uint4*)Wp;
    #pragma unroll
    for (int it = 0; it < 16; ++it) {
        int p = it * 512 + tid;
        int col = p >> 6, ks = p & 63;
        uint4 v = wg4[(t * 128 + col) * 64 + ks];
        int dst = (((col >> 6) * 16 + (ks >> 2)) * 4 + ((col >> 4) & 3)) * 64
                  + (ks & 3) * 16 + (col & 15);
        BshF[dst] = v;
    }
    // ---- table tile [32 v][128 c7]
    const uint4* tg = (const uint4*)table;
    uint4* T4 = (uint4*)Tsh;
    #pragma unroll
    for (int it = 0; it < 2; ++it) {
        int p = it * 512 + tid;
        T4[p] = tg[(p >> 5) * 512 + t * 32 + (p & 31)];
    }
    // ---- msgs [s][row]
    #pragma unroll
    for (int it = 0; it < 8; ++it) {
        int p = it * 512 + tid;
        int row = p >> 6, s_ = p & 63;
        Msh[s_ * 64 + row] = (unsigned char)msgs[(g * 64 + row) * 64 + s_];
    }
    __syncthreads();

    // ---- per-group XCD co-location verdict (leader-decided, bounded, no hang)
    unsigned* xslots = flags + 256;   // 256 words
    unsigned* verd   = flags + 512;   // 16 words
    volatile unsigned* bc = (volatile unsigned*)Hsh;
    if (tid == 0) {
        unsigned xcd;
        asm volatile("s_getreg_b32 %0, hwreg(HW_REG_XCC_ID)" : "=s"(xcd));
        ASTORE(&xslots[g * 16 + t], xcd + 1u);
        if (t == 0) {
            unsigned ok = 1, first = 0;
            long spins = 0;
            for (int i = 0; i < 16 && ok; ++i) {
                unsigned v;
                for (;;) {
                    v = ALOAD(&xslots[g * 16 + i]);
                    if (v) break;
                    if (++spins > (1 << 20)) { ok = 0; break; }   // bounded
                    __builtin_amdgcn_s_sleep(2);
                }
                if (!ok) break;
                if (i == 0) first = v;
                else if (v != first) ok = 0;
            }
            ASTORE(&verd[g], ok + 1u);   // always published
        }
        unsigned v;
        do {
            v = ALOAD(&verd[g]);
            if (!v) __builtin_amdgcn_s_sleep(2);
        } while (!v);                    // leader always publishes -> terminates
        bc[0] = v - 1;
    }
    __syncthreads();
    unsigned fastu = bc[0];
    __syncthreads();   // everyone read verdict before Hsh reuse

    unsigned* myflag = flags + g * 16;
    if (fastu) steps_loop<1>(BshF, Tsh, Msh, Hsh, hb, myflag, g, t);
    else       steps_loop<0>(BshF, Tsh, Msh, Hsh, hb, myflag, g, t);
}

// ---------------------------------------------------------------------------
// hidden = relu([h64, img] @ w1^T + b1): M=1024,N=512,K=1024. Grid (16,16),
// tile 64x32, 4 waves split M. Plain loads (dispatch-boundary coherence).
// ---------------------------------------------------------------------------
__global__ __launch_bounds__(256) void mlp2_k(
    const u64* __restrict__ hfin, const unsigned short* __restrict__ imgb,
    const unsigned short* __restrict__ w1p, const float* __restrict__ b1,
    float* __restrict__ hid)
{
    __shared__ uint4 ldsA[512];   // [64 rows][8 slots]
    __shared__ uint4 ldsB[256];   // [32 cols][8 slots]
    const int tid = threadIdx.x;
    const int lane = tid & 63, wid = tid >> 6;
    const int l15 = lane & 15, l4 = lane >> 4;
    const int mbase = blockIdx.y * 64;
    const int t = blockIdx.x;     // [0,16)

    const uint4* h4 = (const uint4*)hfin;  // h row = 64 uint4 (K=512)
    const uint4* ia = (const uint4*)imgb;
    const uint4* wb = (const uint4*)w1p;   // rows of 128 uint4

    f32x4 acc[2] = {};
    uint4 ra[2], rb1;

    #pragma unroll
    for (int j = 0; j < 2; ++j) {
        int p = tid + j * 256, row = p >> 3, ss = (p & 7) ^ (row & 7);
        ra[j] = h4[(mbase + row) * 64 + ss];
    }
    {
        int col = tid >> 3, ss = (tid & 7) ^ (col & 7);
        rb1 = wb[(t * 32 + col) * 128 + ss];
    }
    #pragma unroll
    for (int j = 0; j < 2; ++j) ldsA[tid + j * 256] = ra[j];
    ldsB[tid] = rb1;
    __syncthreads();

    for (int kc = 0; kc < 16; ++kc) {
        if (kc < 15) {
            int kn = kc + 1;
            #pragma unroll
            for (int j = 0; j < 2; ++j) {
                int p = tid + j * 256, row = p >> 3, ss = (p & 7) ^ (row & 7);
                ra[j] = (kn < 8) ? h4[(mbase + row) * 64 + kn * 8 + ss]
                                 : ia[(mbase + row) * 64 + (kn - 8) * 8 + ss];
            }
            int col = tid >> 3, ss = (tid & 7) ^ (col & 7);
            rb1 = wb[(t * 32 + col) * 128 + kn * 8 + ss];
        }
        #pragma unroll
        for (int kg = 0; kg < 2; ++kg) {
            int row = wid * 16 + l15;
            bf16x8 af = *(const bf16x8*)&ldsA[row * 8 + ((kg * 4 + l4) ^ (row & 7))];
            #pragma unroll
            for (int cf = 0; cf < 2; ++cf) {
                int col = cf * 16 + l15;
                bf16x8 bf = *(const bf16x8*)&ldsB[col * 8 + ((kg * 4 + l4) ^ (col & 7))];
                acc[cf] = __builtin_amdgcn_mfma_f32_16x16x32_bf16(af, bf, acc[cf], 0, 0, 0);
            }
        }
        if (kc < 15) {
            __syncthreads();
            #pragma unroll
            for (int j = 0; j < 2; ++j) ldsA[tid + j * 256] = ra[j];
            ldsB[tid] = rb1;
            __syncthreads();
        }
    }

    #pragma unroll
    for (int reg = 0; reg < 4; ++reg) {
        int b = mbase + wid * 16 + l4 * 4 + reg;
        #pragma unroll
        for (int cf = 0; cf < 2; ++cf) {
            int n = t * 32 + cf * 16 + l15;
            hid[b * 512 + n] = fmaxf(acc[cf][reg] + b1[n], 0.f);
        }
    }
}

// prediction: one wave per batch row, shuffle-reduce over 512 f32.
__global__ __launch_bounds__(256) void pred2_k(
    const float* __restrict__ hid, const float* __restrict__ w2,
    const float* __restrict__ b2, float* __restrict__ out)
{
    int wid = threadIdx.x >> 6, lane = threadIdx.x & 63;
    int b = blockIdx.x * 4 + wid;
    const float4* hr = (const float4*)(hid + b * 512);
    const float4* wA = (const float4*)(w2);
    const float4* wB = (const float4*)(w2 + 512);
    float a0 = 0.f, a1 = 0.f;
    #pragma unroll
    for (int j = 0; j < 2; ++j) {
        float4 h4 = hr[lane * 2 + j];
        float4 x0 = wA[lane * 2 + j], x1 = wB[lane * 2 + j];
        a0 += h4.x * x0.x + h4.y * x0.y + h4.z * x0.z + h4.w * x0.w;
        a1 += h4.x * x1.x + h4.y * x1.y + h4.z * x1.z + h4.w * x1.w;
    }
    #pragma unroll
    for (int off = 32; off > 0; off >>= 1) {
        a0 += __shfl_xor(a0, off);
        a1 += __shfl_xor(a1, off);
    }
    if (lane == 0) {
        out[b * 2]     = a0 + b2[0];
        out[b * 2 + 1] = a1 + b2[1];
    }
}

// emb output gather: out[b][s][:] = embedding[msg[b][s]][:]
__global__ __launch_bounds__(256) void gather_k(
    const float* __restrict__ emb, const int* __restrict__ msgs,
    float* __restrict__ out)
{
    const float4* e4 = (const float4*)emb;
    float4* o4 = (float4*)out;
    int id = blockIdx.x * 256 + threadIdx.x;
    #pragma unroll
    for (int it = 0; it < 4; ++it) {
        int p = id + it * 1048576;
        int bs = p >> 6, e = p & 63;
        int v = msgs[bs];
        o4[p] = e4[v * 64 + e];
    }
}

extern "C" void kernel_launch(void* const* d_in, const int* in_sizes, int n_in,
                              void* d_out, int out_size, void* d_ws, size_t ws_size,
                              hipStream_t stream)
{
    const float* imgr  = (const float*)d_in[0];
    const int*   msgs  = (const int*)d_in[1];
    const float* emb   = (const float*)d_in[2];
    const float* w_ih  = (const float*)d_in[3];
    const float* w_hh  = (const float*)d_in[4];
    const float* b_ih  = (const float*)d_in[5];
    const float* b_hh  = (const float*)d_in[6];
    const float* procw = (const float*)d_in[7];
    const float* procb = (const float*)d_in[8];
    const float* w1    = (const float*)d_in[9];
    const float* b1    = (const float*)d_in[10];
    const float* w2    = (const float*)d_in[11];
    const float* b2    = (const float*)d_in[12];
    float* outp = (float*)d_out;

    // Layout: table 256K | Wp 2M | h[8] 8M | imgb 1M | w1p 1M | hid 2M | flags 4K
    const size_t OFF_WP   = 262144;
    const size_t OFF_H    = 2359296;
    const size_t OFF_IMGB = OFF_H + 8388608;         // 10747904
    const size_t OFF_W1P  = OFF_IMGB + 1048576;      // 11796480
    const size_t OFF_HID  = OFF_W1P + 1048576;       // 12845056
    const size_t OFF_FLG  = OFF_HID + 2097152;       // 14942208
    const size_t NEED     = OFF_FLG + 4096;          // ~14.3 MB
    // Fallback scratch: emb output region (67 MB) is written LAST by gather_k.
    char* ws = (ws_size >= NEED) ? (char*)d_ws : (char*)(outp + 2048);

    float*          table = (float*)(ws);
    unsigned short* Wp    = (unsigned short*)(ws + OFF_WP);
    u64*            hb    = (u64*)(ws + OFF_H);      // 8 x 1 MB rotation
    unsigned short* imgb  = (unsigned short*)(ws + OFF_IMGB);
    unsigned short* w1p   = (unsigned short*)(ws + OFF_W1P);
    float*          hid   = (float*)(ws + OFF_HID);
    unsigned*       flags = (unsigned*)(ws + OFF_FLG);

    hipMemsetAsync(flags, 0, 4096, stream);
    hipFuncSetAttribute((const void*)lstm_k,
                        hipFuncAttributeMaxDynamicSharedMemorySize, 156672);

    prep_k<<<3072, 256, 0, stream>>>(emb, w_ih, b_ih, b_hh, w_hh, w1, imgr,
                                     procw, procb, table, Wp, w1p, imgb);
    lstm_k<<<256, 512, 156672, stream>>>(table, Wp, msgs, hb, flags);
    // final h is buffer (63 & 7) = 7
    mlp2_k<<<dim3(16, 16), 256, 0, stream>>>(hb + (size_t)7 * 131072, imgb,
                                             w1p, b1, hid);
    pred2_k<<<256, 256, 0, stream>>>(hid, w2, b2, outp);
    gather_k<<<4096, 256, 0, stream>>>(emb, msgs, outp + 2048);
}